// Round 1
// baseline (231.527 us; speedup 1.0000x reference)
//
#include <hip/hip_runtime.h>
#include <math.h>

typedef _Float16 h4_t __attribute__((ext_vector_type(4)));
typedef _Float16 h8_t __attribute__((ext_vector_type(8)));
typedef float    f4_t __attribute__((ext_vector_type(4)));

#define NB 128
#define NC 256
#define NQ 64
#define NN 4096
#define TN 64
#define NTILES 64   // NN/TN

// ---------------- K0a: x_k projection, tanh, and exp bound M[b] ----------------
__global__ void k0a(const float* __restrict__ wk, const float* __restrict__ bk,
                    const float* __restrict__ xkey, float* __restrict__ kt,
                    float* __restrict__ Mb)
{
    const int b = blockIdx.x;       // 128 blocks
    const int o = threadIdx.x;      // 64 threads
    float a = bk[o];
    #pragma unroll 8
    for (int c = 0; c < NC; ++c)
        a += wk[o * NC + c] * xkey[b * NC + c];
    float t = tanhf(a);
    kt[b * NQ + o] = t;
    float m = fabsf(t);
    #pragma unroll
    for (int mm = 1; mm < 64; mm <<= 1) m += __shfl_xor(m, mm);
    if (o == 0) Mb[b] = m;
}

// ---------------- K0b: pack wq into MFMA fragment order (fp16) + transpose wv, wt ----
__global__ void k0b(const float* __restrict__ wq, const float* __restrict__ wvm,
                    const float* __restrict__ wtm, _Float16* __restrict__ wqf,
                    float* __restrict__ wvT, float* __restrict__ wtT)
{
    const int i = blockIdx.x * 256 + threadIdx.x;
    if (i < 16384) {
        // wqf[((f*64 + lane)*4 + j)]: f = ks*4 + t; B-frag: k = 16ks + 4*(lane>>4)+j, n = 16t + (lane&15)
        const int j = i & 3;
        const int l = (i >> 2) & 63;
        const int f = i >> 8;
        const int ks = f >> 2, t = f & 3;
        const int o = t * 16 + (l & 15);
        const int c = ks * 16 + (l >> 4) * 4 + j;
        wqf[i] = (_Float16)wq[o * NC + c];
    } else if (i < 16384 + 65536) {
        const int ii = i - 16384;
        const int k = ii >> 8, c = ii & 255;
        wvT[k * NC + c] = wvm[c * NC + k];
    } else if (i < 16384 + 131072) {
        const int ii = i - 16384 - 65536;
        const int k = ii >> 8, c = ii & 255;
        wtT[k * NC + c] = wtm[c * NC + k];
    }
}

// ---------------- K1: fused main pass over x (read x once) ----------------
// per block: one (b, n-tile of 64). Stage x[b,:,n0:n0+64] as fp16 [n][c] in LDS
// (XOR-swizzled), MFMA x_q, tanh-energy vs kt, w = exp(e - M), partial weighted sums.
template<int ATOMIC>
__global__ __launch_bounds__(256, 4) void k_main(
    const float* __restrict__ x, const _Float16* __restrict__ wqf,
    const float* __restrict__ bq, const float* __restrict__ kt,
    const float* __restrict__ Mb, float* __restrict__ w_out,
    float* __restrict__ spart, float* __restrict__ zpart,
    float* __restrict__ sraw, float* __restrict__ Zg)
{
    __shared__ _Float16 xl[64 * 256];
    __shared__ float e_l[64];
    __shared__ float w_l[64];

    const int bid  = blockIdx.x;
    const int b    = bid >> 6;
    const int tile = bid & 63;
    const int n0   = tile * TN;
    const int tid  = threadIdx.x;

    // ---- stage x tile: lane<->n (coalesced 256B/instr), 64 c per thread
    {
        const int n  = tid & 63;
        const int cg = tid >> 6;   // 0..3
        const float* src = x + ((size_t)b * NC + cg * 64) * NN + n0 + n;
        #pragma unroll
        for (int p = 0; p < 2; ++p) {
            float v[32];
            #pragma unroll
            for (int i = 0; i < 32; ++i)
                v[i] = src[(size_t)(p * 32 + i) * NN];
            #pragma unroll
            for (int k8 = 0; k8 < 4; ++k8) {
                h8_t h;
                #pragma unroll
                for (int j = 0; j < 8; ++j) h[j] = (_Float16)v[k8 * 8 + j];
                const int c   = cg * 64 + p * 32 + k8 * 8;
                const int idx = (n * 256 + c) ^ ((n & 7) << 3);
                *(h8_t*)&xl[idx] = h;
            }
        }
    }
    __syncthreads();

    // ---- MFMA: x_q[n, o] for n in tile, o in 0..63  (fp16 in, fp32 acc)
    const int wid  = tid >> 6;
    const int lane = tid & 63;
    const int g    = lane >> 4;
    const int li   = lane & 15;

    f4_t acc[4];
    #pragma unroll
    for (int t = 0; t < 4; ++t) acc[t] = f4_t{0.f, 0.f, 0.f, 0.f};

    #pragma unroll
    for (int ks = 0; ks < 16; ++ks) {
        const int n    = wid * 16 + li;          // A row m = lane&15
        const int cA   = ks * 16 + g * 4;        // A k   = 4*(lane>>4)+j
        const int idxA = (n * 256 + cA) ^ ((n & 7) << 3);
        h4_t a = *(const h4_t*)&xl[idxA];
        #pragma unroll
        for (int t = 0; t < 4; ++t) {
            h4_t bf = *(const h4_t*)&wqf[(size_t)((ks * 4 + t) * 64 + lane) * 4];
            acc[t] = __builtin_amdgcn_mfma_f32_16x16x16f16(a, bf, acc[t], 0, 0, 0);
        }
    }

    // ---- energy: e[n] = sum_o tanh(x_q + bq)*kt ; D row = 4g+r, col = 16t+li
    {
        float ep[4] = {0.f, 0.f, 0.f, 0.f};
        #pragma unroll
        for (int t = 0; t < 4; ++t) {
            const int o = t * 16 + li;
            const float kto = kt[b * NQ + o];
            const float bqo = bq[o];
            #pragma unroll
            for (int r = 0; r < 4; ++r)
                ep[r] += tanhf(acc[t][r] + bqo) * kto;
        }
        #pragma unroll
        for (int r = 0; r < 4; ++r) {
            #pragma unroll
            for (int m = 1; m < 16; m <<= 1)
                ep[r] += __shfl_xor(ep[r], m);
        }
        if (li == 0) {
            #pragma unroll
            for (int r = 0; r < 4; ++r)
                e_l[wid * 16 + g * 4 + r] = ep[r];
        }
    }
    __syncthreads();

    // ---- w = exp(e - M[b]) ; per-tile partial Z
    if (tid < 64) {
        const float e   = e_l[tid];
        const float wgt = expf(e - Mb[b]);
        w_l[tid] = wgt;
        w_out[b * NN + n0 + tid] = wgt;
        float z = wgt;
        #pragma unroll
        for (int m = 1; m < 64; m <<= 1) z += __shfl_xor(z, m);
        if (tid == 0) {
            if (ATOMIC) atomicAdd(&Zg[b], z);
            else        zpart[b * NTILES + tile] = z;
        }
    }
    __syncthreads();

    // ---- partial weighted sum: s[c] = sum_n x[c,n]*w[n]
    {
        float a2 = 0.f;
        #pragma unroll 8
        for (int n = 0; n < 64; ++n) {
            const int idx = (n * 256 + tid) ^ ((n & 7) << 3);
            a2 += (float)xl[idx] * w_l[n];
        }
        if (ATOMIC) atomicAdd(&sraw[b * NC + tid], a2);
        else        spart[((size_t)(b * NTILES + tile)) * NC + tid] = a2;
    }
}

// ---------------- K2: per-batch reduce + x_r + t_pre ----------------
__global__ void k2(const float* __restrict__ spart, const float* __restrict__ zpart,
                   const float* __restrict__ sraw,  const float* __restrict__ Zg,
                   const float* __restrict__ wvT,   const float* __restrict__ wtT,
                   const float* __restrict__ bv,    const float* __restrict__ bt,
                   const float* __restrict__ xkey,  float* __restrict__ tpre,
                   float* __restrict__ Zout, int atomicMode)
{
    const int b = blockIdx.x;
    const int tid = threadIdx.x;
    __shared__ float s_l[NC];
    __shared__ float d_l[NC];
    __shared__ float zsh;

    float ssum;
    if (atomicMode) {
        ssum = sraw[b * NC + tid];
        if (tid == 0) { zsh = Zg[b]; Zout[b] = zsh; }
    } else {
        ssum = 0.f;
        #pragma unroll 8
        for (int T = 0; T < NTILES; ++T)
            ssum += spart[((size_t)(b * NTILES + T)) * NC + tid];
        if (tid < 64) {
            float z = zpart[b * NTILES + tid];
            #pragma unroll
            for (int m = 1; m < 64; m <<= 1) z += __shfl_xor(z, m);
            if (tid == 0) { zsh = z; Zout[b] = z; }
        }
    }
    s_l[tid] = ssum;
    __syncthreads();

    const float invZ = 1.0f / zsh;
    // x_r[c] = bv[c] + sum_k wv[c][k] * s_norm[k]
    float a = bv[tid];
    #pragma unroll 8
    for (int k = 0; k < NC; ++k)
        a += wvT[k * NC + tid] * (s_l[k] * invZ);
    d_l[tid] = xkey[b * NC + tid] - a;
    __syncthreads();
    // t_pre[c] = bt[c] + sum_k wt[c][k] * d[k]
    float t = bt[tid];
    #pragma unroll 8
    for (int k = 0; k < NC; ++k)
        t += wtT[k * NC + tid] * d_l[k];
    tpre[b * NC + tid] = t;
}

// ---------------- K3: BatchNorm over batch + ReLU + residual ----------------
__global__ void k3(const float* __restrict__ tpre, const float* __restrict__ xkey,
                   const float* __restrict__ gma, const float* __restrict__ bta,
                   float* __restrict__ out)
{
    const int c = threadIdx.x;   // 256 threads, 1 block
    float s = 0.f, s2 = 0.f;
    #pragma unroll 8
    for (int b = 0; b < NB; ++b) {
        const float v = tpre[b * NC + c];
        s += v; s2 += v * v;
    }
    const float mean = s * (1.f / NB);
    const float var  = s2 * (1.f / NB) - mean * mean;
    const float rs   = rsqrtf(var + 1e-5f);
    const float gc = gma[c], bc = bta[c];
    #pragma unroll 8
    for (int b = 0; b < NB; ++b) {
        float v = (tpre[b * NC + c] - mean) * rs * gc + bc;
        v = v > 0.f ? v : 0.f;
        out[b * NC + c] = xkey[b * NC + c] + v;
    }
}

// ---------------- K4: attention = w / Z ----------------
__global__ void k4(const float* __restrict__ w, const float* __restrict__ Z,
                   float* __restrict__ out)
{
    const int i = blockIdx.x * 256 + threadIdx.x;   // 524288
    const int b = i >> 12;
    out[i] = w[i] / Z[b];
}

extern "C" void kernel_launch(void* const* d_in, const int* in_sizes, int n_in,
                              void* d_out, int out_size, void* d_ws, size_t ws_size,
                              hipStream_t stream)
{
    const float* x    = (const float*)d_in[0];
    const float* xkey = (const float*)d_in[1];
    const float* wq   = (const float*)d_in[2];
    const float* bq   = (const float*)d_in[3];
    const float* wk   = (const float*)d_in[4];
    const float* bk   = (const float*)d_in[5];
    const float* wvm  = (const float*)d_in[6];
    const float* bv   = (const float*)d_in[7];
    const float* wtm  = (const float*)d_in[8];
    const float* bt   = (const float*)d_in[9];
    const float* gma  = (const float*)d_in[10];
    const float* bta  = (const float*)d_in[11];
    float* out = (float*)d_out;

    char* ws = (char*)d_ws;
    size_t off = 0;
    auto take = [&](size_t bytes) -> char* {
        char* p = ws + off;
        off = (off + bytes + 255) & ~(size_t)255;
        return p;
    };
    _Float16* wqf  = (_Float16*)take(16384 * 2);
    float* kt   = (float*)take(NB * NQ * 4);
    float* Mb   = (float*)take(NB * 4);
    float* wbuf = (float*)take((size_t)NB * NN * 4);
    float* wvT  = (float*)take(65536 * 4);
    float* wtT  = (float*)take(65536 * 4);
    float* tpre = (float*)take(NB * NC * 4);
    float* Zf   = (float*)take(NB * 4);

    const size_t base = off;
    float* spart = (float*)take((size_t)NB * NTILES * NC * 4);
    float* zpart = (float*)take(NB * NTILES * 4);
    const bool det = (off <= ws_size);
    float* sraw = nullptr;
    float* Zg   = nullptr;
    if (!det) {
        off = base;
        sraw = (float*)take(NB * NC * 4);
        Zg   = (float*)take(NB * 4);
        hipMemsetAsync(sraw, 0, NB * NC * 4, stream);
        hipMemsetAsync(Zg, 0, NB * 4, stream);
    }

    k0a<<<NB, 64, 0, stream>>>(wk, bk, xkey, kt, Mb);
    k0b<<<576, 256, 0, stream>>>(wq, wvm, wtm, wqf, wvT, wtT);
    if (det)
        k_main<0><<<NB * NTILES, 256, 0, stream>>>(x, wqf, bq, kt, Mb, wbuf,
                                                   spart, zpart, nullptr, nullptr);
    else
        k_main<1><<<NB * NTILES, 256, 0, stream>>>(x, wqf, bq, kt, Mb, wbuf,
                                                   nullptr, nullptr, sraw, Zg);
    k2<<<NB, 256, 0, stream>>>(spart, zpart, sraw, Zg, wvT, wtT, bv, bt, xkey,
                               tpre, Zf, det ? 0 : 1);
    k3<<<1, 256, 0, stream>>>(tpre, xkey, gma, bta, out);
    k4<<<2048, 256, 0, stream>>>(wbuf, Zf, out + NB * NC);
}